// Round 3
// baseline (127.913 us; speedup 1.0000x reference)
//
#include <hip/hip_runtime.h>

// Sliding-window attention, window=127 (+-63), B=4 L=4096 NH=16 H=64, fp32 in/out.
// Round-3: recombination of measured-good parts.
//  - R1 LDS-staged epilogue restored (R2's direct scattered stores caused 2x WRITE_SIZE via
//    partial-line RMW); O normalized in-register first -> no D_lds, O aliases V in 32 KiB.
//  - LDS 32768 B exactly -> 5 blocks/CU (160 KiB), occupancy 38% -> ~60%.
//  - V_lds dense [64][256] f16 + XOR swizzle (R2: conflicts 3.9M -> 1.2M). Kept.
//  - K register prefetch pinned with sched_barrier(0) right after issue (R2's prefetch was
//    sunk by the scheduler: VGPR stayed 64).

typedef _Float16 f16;
typedef _Float16 f16x2  __attribute__((ext_vector_type(2)));
typedef _Float16 f16x8  __attribute__((ext_vector_type(8)));
typedef float    f32x16 __attribute__((ext_vector_type(16)));
typedef int      int4v  __attribute__((ext_vector_type(4)));

constexpr int NB = 4, L = 4096, NH = 16, H = 64;
constexpr int CQ = 128, NC = L / CQ, KW = 256, WR = 63;
constexpr int RS = NH * H;   // seq-row stride in floats

#define DEV static __device__ __forceinline__

DEV int iclamp(int x, int lo, int hi) { return x < lo ? lo : (x > hi ? hi : x); }

DEV float fexp2(float x) {
#if __has_builtin(__builtin_amdgcn_exp2f)
    return __builtin_amdgcn_exp2f(x);
#else
    return exp2f(x);
#endif
}

DEV int packh2(float a, float b) {
    f16x2 p; p.x = (f16)a; p.y = (f16)b;   // RNE casts
    return __builtin_bit_cast(int, p);
}

// byte offset of (row h, key byte kb) in swizzled V_lds
DEV int vaddr(int h, int kb) {
    return (h * 512 + kb) ^ ((((h & 7) ^ ((h >> 3) & 7))) << 4);
}

// float index of (row q, col h) in swizzled O_lds
DEV int oaddr(int row, int col) {
    return (row * 64 + col) ^ ((row & 3) << 2);
}

// After call: new_a[l<32]=a[l], new_a[l>=32]=b[l^32]; new_b[l<32]=a[l^32], new_b[l>=32]=b[l].
DEV void swap_halves(int& a, int& b, int hi) {
    int pa = __shfl_xor(a, 32, 64);
    int pb = __shfl_xor(b, 32, 64);
    int na = hi ? pb : a;
    int nb = hi ? b  : pa;
    a = na; b = nb;
}

__global__ __launch_bounds__(256, 4)
void wattn_kernel(const float* __restrict__ q_, const float* __restrict__ k_,
                  const float* __restrict__ v_, float* __restrict__ o_)
{
    __shared__ alignas(16) char smem[32768];   // V^T (f16, swizzled) then O (f32, swizzled)
    char*  V_lds = smem;
    float* O_lds = (float*)smem;

    // XCD-aware swizzle: 2048 blocks, 8 XCDs, 2048%8==0 -> bijective
    const int bid = (int)blockIdx.x;
    const int wid = (bid & 7) * ((NB * NH * NC) / 8) + (bid >> 3);
    const int c = wid & (NC - 1);
    const int n = (wid >> 5) & (NH - 1);
    const int b = wid >> 9;

    const int t    = (int)threadIdx.x;
    const int lane = t & 63;
    const int wq   = t >> 6;       // wave id = 32-query tile
    const int lq   = lane & 31;
    const int hi   = lane >> 5;

    const int kg0 = c * CQ - WR;                       // global seq row of window key j=0
    const size_t bn = ((size_t)b * L * NH + n) * H;    // element offset of (b,0,n,0)

    // ---- stage V transposed into swizzled LDS (coalesced float4 loads, f16x2 writes) ----
    {
        const int r0_ = ((t & 255) >> 4) << 1;   // base even key row handled by this thread
        const int h4  = (t & 15) << 2;
        #pragma unroll
        for (int p = 0; p < 8; ++p) {
            int r0  = r0_ + p * 32;
            int kr0 = iclamp(kg0 + r0,     0, L - 1);
            int kr1 = iclamp(kg0 + r0 + 1, 0, L - 1);
            float4 v0 = *(const float4*)(v_ + bn + (size_t)kr0 * RS + h4);
            float4 v1 = *(const float4*)(v_ + bn + (size_t)kr1 * RS + h4);
            *(f16x2*)(V_lds + vaddr(h4 + 0, r0 * 2)) = (f16x2){(f16)v0.x, (f16)v1.x};
            *(f16x2*)(V_lds + vaddr(h4 + 1, r0 * 2)) = (f16x2){(f16)v0.y, (f16)v1.y};
            *(f16x2*)(V_lds + vaddr(h4 + 2, r0 * 2)) = (f16x2){(f16)v0.z, (f16)v1.z};
            *(f16x2*)(V_lds + vaddr(h4 + 3, r0 * 2)) = (f16x2){(f16)v0.w, (f16)v1.w};
        }
    }

    // ---- Q fragments (B-operand: lane holds Q[q=lq][h = 16*tq + 8*hi + j]) ----
    const int iq = wq * 32 + lq;
    const float qs = 0.125f * 1.44269504088896f;   // h^-0.5 * log2(e)
    const float* qrow = q_ + bn + (size_t)(c * CQ + iq) * RS + hi * 8;
    f16x8 qf[4];
    #pragma unroll
    for (int tq = 0; tq < 4; ++tq) {
        float4 a  = *(const float4*)(qrow + tq * 16);
        float4 b2 = *(const float4*)(qrow + tq * 16 + 4);
        qf[tq] = (f16x8){(f16)(a.x * qs),  (f16)(a.y * qs),  (f16)(a.z * qs),  (f16)(a.w * qs),
                         (f16)(b2.x * qs), (f16)(b2.y * qs), (f16)(b2.z * qs), (f16)(b2.w * qs)};
    }

    // ---- K tile loader (raw float4, converted at use) ----
    const float* kbase = k_ + bn + hi * 8;
    float4 kraw[8];
    auto kload = [&](int kt) {
        int kg = iclamp(kg0 + kt * 32 + lq, 0, L - 1);
        const float* krow = kbase + (size_t)kg * RS;
        #pragma unroll
        for (int tq = 0; tq < 4; ++tq) {
            kraw[2 * tq]     = *(const float4*)(krow + tq * 16);
            kraw[2 * tq + 1] = *(const float4*)(krow + tq * 16 + 4);
        }
    };
    kload(wq);   // first tile in flight before the barrier

    // window mask bounds: allowed local keys j with j-iq in [0,126] and kg0+j in [0,L)
    const int jlo = (c == 0) ? WR : 0;
    const int jhi = (KW < L - kg0) ? KW : (L - kg0);
    const int lo  = (iq > jlo) ? iq : jlo;
    const int hb  = (iq + 126 < jhi - 1) ? (iq + 126) : (jhi - 1);
    const unsigned span = (unsigned)(hb - lo);

    f32x16 o0, o1;
    #pragma unroll
    for (int r = 0; r < 16; ++r) { o0[r] = 0.f; o1[r] = 0.f; }
    float dsum = 0.f;

    __syncthreads();

    #pragma unroll
    for (int i = 0; i < 5; ++i) {
        const int kt = wq + i;
        // convert current raw K to f16 fragments, freeing kraw for the prefetch
        f16x8 kf[4];
        #pragma unroll
        for (int tq = 0; tq < 4; ++tq) {
            float4 ka = kraw[2 * tq], kb2 = kraw[2 * tq + 1];
            kf[tq] = (f16x8){(f16)ka.x,  (f16)ka.y,  (f16)ka.z,  (f16)ka.w,
                             (f16)kb2.x, (f16)kb2.y, (f16)kb2.z, (f16)kb2.w};
        }
        if (i < 4) {
            kload(kt + 1);                        // prefetch next tile
            __builtin_amdgcn_sched_barrier(0);    // pin the loads HERE — don't sink to use
        }

        // ---- S^T tile = K_tile(32k x 64h) . Q^T ----
        f32x16 s;
        #pragma unroll
        for (int r = 0; r < 16; ++r) s[r] = 0.f;
        #pragma unroll
        for (int tq = 0; tq < 4; ++tq)
            s = __builtin_amdgcn_mfma_f32_32x32x16_f16(kf[tq], qf[tq], s, 0, 0, 0);

        // ---- mask + exp2 + denominator (per-lane: q = lq) ----
        const int jb = kt * 32 + 4 * hi;
        float pe[16];
        #pragma unroll
        for (int r = 0; r < 16; ++r) {
            int j = jb + (r & 3) + ((r >> 2) << 3);      // D-row -> local key index
            float e = fexp2(s[r]);
            e = ((unsigned)(j - lo) <= span) ? e : 0.f;
            dsum += e;
            pe[r] = e;
        }
        // ---- P fragments: pack to f16 pairs, exchange across lane halves -> A-operand ----
        int d0 = packh2(pe[0],  pe[1]),  d1 = packh2(pe[2],  pe[3]);
        int d2 = packh2(pe[4],  pe[5]),  d3 = packh2(pe[6],  pe[7]);
        int d4 = packh2(pe[8],  pe[9]),  d5 = packh2(pe[10], pe[11]);
        int d6 = packh2(pe[12], pe[13]), d7 = packh2(pe[14], pe[15]);
        swap_halves(d0, d2, hi); swap_halves(d1, d3, hi);
        swap_halves(d4, d6, hi); swap_halves(d5, d7, hi);
        f16x8 pa0 = __builtin_bit_cast(f16x8, (int4v){d0, d1, d2, d3});   // keys kt*32 + 0..15
        f16x8 pa1 = __builtin_bit_cast(f16x8, (int4v){d4, d5, d6, d7});   // keys kt*32 + 16..31

        // ---- PV: O[32q][64h] += P . V, B-operand from swizzled transposed V in LDS ----
        const int kb = kt * 64 + hi * 16;   // key byte base for this lane's k-slots
        f16x8 vb00 = *(const f16x8*)(V_lds + vaddr(lq,      kb));
        f16x8 vb01 = *(const f16x8*)(V_lds + vaddr(lq,      kb + 32));
        f16x8 vb10 = *(const f16x8*)(V_lds + vaddr(32 + lq, kb));
        f16x8 vb11 = *(const f16x8*)(V_lds + vaddr(32 + lq, kb + 32));
        o0 = __builtin_amdgcn_mfma_f32_32x32x16_f16(pa0, vb00, o0, 0, 0, 0);
        o0 = __builtin_amdgcn_mfma_f32_32x32x16_f16(pa1, vb01, o0, 0, 0, 0);
        o1 = __builtin_amdgcn_mfma_f32_32x32x16_f16(pa0, vb10, o1, 0, 0, 0);
        o1 = __builtin_amdgcn_mfma_f32_32x32x16_f16(pa1, vb11, o1, 0, 0, 0);
    }

    // ---- denominators: full per-query sum, reciprocal, per-row redistribute ----
    float dtot = dsum + __shfl_xor(dsum, 32, 64);
    float dinv = 1.0f / dtot;

    __syncthreads();   // all waves done reading V_lds; reuse LDS for O staging

    // normalized O fragments -> swizzled LDS (row q = wq*32 + (r&3)+8*(r>>2)+4*hi)
    #pragma unroll
    for (int r = 0; r < 16; ++r) {
        int qloc = (r & 3) + ((r >> 2) << 3) + 4 * hi;
        float rd = __shfl(dinv, qloc, 64);     // dinv of query qloc lives in lane qloc
        int row = wq * 32 + qloc;
        O_lds[oaddr(row, lq)]      = o0[r] * rd;
        O_lds[oaddr(row, 32 + lq)] = o1[r] * rd;
    }
    __syncthreads();

    // coalesced float4 stores: out[b][c*128+row][n][h]
    const size_t ob = ((size_t)b * L + (size_t)c * CQ) * RS + (size_t)n * H;
    #pragma unroll
    for (int it = 0; it < 8; ++it) {
        int flat = it * 256 + t;
        int row  = flat >> 4;
        int h4   = (flat & 15) << 2;
        float4 val = *(const float4*)(O_lds + oaddr(row, h4));
        *(float4*)(o_ + ob + (size_t)row * RS + h4) = val;
    }
}

extern "C" void kernel_launch(void* const* d_in, const int* in_sizes, int n_in,
                              void* d_out, int out_size, void* d_ws, size_t ws_size,
                              hipStream_t stream) {
    const float* q = (const float*)d_in[0];
    const float* k = (const float*)d_in[1];
    const float* v = (const float*)d_in[2];
    float* o = (float*)d_out;
    (void)in_sizes; (void)n_in; (void)out_size; (void)d_ws; (void)ws_size;
    wattn_kernel<<<dim3(NB * NH * NC), dim3(256), 0, stream>>>(q, k, v, o);
}

// Round 4
// 54.421 us; speedup vs baseline: 2.3504x; 2.3504x over previous
//
#include <hip/hip_runtime.h>

// Sliding-window attention, window=127 (+-63), B=4 L=4096 NH=16 H=64, fp32 in/out.
// Round-4: kill the strided global reads (R1-R3 were TA/latency-bound: each K/Q float4
// touched 32 distinct cache lines because lanes map to 4KB-strided rows).
//  - Q,K,V all staged ONCE per block into LDS as f16 via coalesced float4 loads
//    (16 threads per 256B row). Inner loop is pure ds_read_b128 + MFMA + VALU.
//  - Q/K row-major [row][64h] f16, XOR swizzle addr ^= (row&7)<<4  (G4 pattern).
//  - V transposed [64h][256k] f16 with the R2-proven vaddr swizzle.
//  - LDS 80KB -> 2 blocks/CU. amdgpu_waves_per_eu(2,2) => 256-VGPR budget: no spill
//    pathology (R3: allocator stuck at 64 VGPRs -> 120MB scratch writes).
//  - Epilogue: R3's O->LDS (aliases Q/K after barrier) + coalesced float4 stores (64MB exact).

typedef _Float16 f16;
typedef _Float16 f16x2  __attribute__((ext_vector_type(2)));
typedef _Float16 f16x4  __attribute__((ext_vector_type(4)));
typedef _Float16 f16x8  __attribute__((ext_vector_type(8)));
typedef float    f32x16 __attribute__((ext_vector_type(16)));
typedef int      int4v  __attribute__((ext_vector_type(4)));

constexpr int NB = 4, L = 4096, NH = 16, H = 64;
constexpr int CQ = 128, NC = L / CQ, KW = 256, WR = 63;
constexpr int RS = NH * H;   // seq-row stride in floats

constexpr int Q_OFF = 0;         // [128][64] f16, 128B rows, swizzled
constexpr int K_OFF = 16384;     // [256][64] f16, 128B rows, swizzled
constexpr int V_OFF = 49152;     // [64][256] f16 transposed, swizzled
constexpr int LDS_BYTES = 81920; // 80 KiB -> 2 blocks/CU

#define DEV static __device__ __forceinline__

DEV int iclamp(int x, int lo, int hi) { return x < lo ? lo : (x > hi ? hi : x); }

DEV float fexp2(float x) {
#if __has_builtin(__builtin_amdgcn_exp2f)
    return __builtin_amdgcn_exp2f(x);
#else
    return exp2f(x);
#endif
}

DEV int packh2(float a, float b) {
    f16x2 p; p.x = (f16)a; p.y = (f16)b;   // RNE casts
    return __builtin_bit_cast(int, p);
}

// byte offset in row-major [R][64] f16 tile (128B rows), bank-conflict swizzle
DEV int rmaddr(int row, int colb) {
    return row * 128 + (colb ^ ((row & 7) << 4));
}

// byte offset of (row h, key byte kb) in transposed V_lds (512B rows)
DEV int vaddr(int h, int kb) {
    return (h * 512 + kb) ^ ((((h & 7) ^ ((h >> 3) & 7))) << 4);
}

// float index of (row q, col h) in swizzled O_lds
DEV int oaddr(int row, int col) {
    return (row * 64 + col) ^ ((row & 3) << 2);
}

// After call: new_a[l<32]=a[l], new_a[l>=32]=b[l^32]; new_b[l<32]=a[l^32], new_b[l>=32]=b[l].
DEV void swap_halves(int& a, int& b, int hi) {
    int pa = __shfl_xor(a, 32, 64);
    int pb = __shfl_xor(b, 32, 64);
    int na = hi ? pb : a;
    int nb = hi ? b  : pa;
    a = na; b = nb;
}

__global__ __launch_bounds__(256) __attribute__((amdgpu_waves_per_eu(2, 2)))
void wattn_kernel(const float* __restrict__ q_, const float* __restrict__ k_,
                  const float* __restrict__ v_, float* __restrict__ o_)
{
    __shared__ alignas(16) char smem[LDS_BYTES];
    char*  Q_lds = smem + Q_OFF;
    char*  K_lds = smem + K_OFF;
    char*  V_lds = smem + V_OFF;
    float* O_lds = (float*)smem;       // aliases Q+K region after the post-loop barrier

    // XCD-aware swizzle: 2048 blocks, 8 XCDs, 2048%8==0 -> bijective
    const int bid = (int)blockIdx.x;
    const int wid = (bid & 7) * ((NB * NH * NC) / 8) + (bid >> 3);
    const int c = wid & (NC - 1);
    const int n = (wid >> 5) & (NH - 1);
    const int b = wid >> 9;

    const int t    = (int)threadIdx.x;
    const int lane = t & 63;
    const int wq   = t >> 6;       // wave id = 32-query tile
    const int lq   = lane & 31;
    const int hi   = lane >> 5;

    const int kg0 = c * CQ - WR;                       // global seq row of window key j=0
    const size_t bn = ((size_t)b * L * NH + n) * H;    // element offset of (b,0,n,0)
    const float qs = 0.125f * 1.44269504088896f;       // h^-0.5 * log2(e)

    // ---- cooperative staging: all global reads coalesced (16 threads per 256B row) ----
    const int rr = t >> 4;           // 0..15
    const int h4 = (t & 15) << 2;    // float col 0,4,..,60
    const int cb = h4 << 1;          // f16 byte col = (t&15)*8

    // Q: scaled f16, rows 0..127
    {
        const float* qp = q_ + bn + (size_t)(c * CQ) * RS + h4;
        #pragma unroll
        for (int p = 0; p < 8; ++p) {
            int r = rr + p * 16;
            float4 x = *(const float4*)(qp + (size_t)r * RS);
            *(f16x4*)(Q_lds + rmaddr(r, cb)) =
                (f16x4){(f16)(x.x * qs), (f16)(x.y * qs), (f16)(x.z * qs), (f16)(x.w * qs)};
        }
    }
    // K: rows 0..255 (window keys, edge-clamped; masked in softmax)
    {
        #pragma unroll
        for (int p = 0; p < 16; ++p) {
            int r  = rr + p * 16;
            int kr = iclamp(kg0 + r, 0, L - 1);
            float4 x = *(const float4*)(k_ + bn + (size_t)kr * RS + h4);
            *(f16x4*)(K_lds + rmaddr(r, cb)) =
                (f16x4){(f16)x.x, (f16)x.y, (f16)x.z, (f16)x.w};
        }
    }
    // V: transposed [64h][256k]
    {
        const int r0_ = (t >> 4) << 1;
        #pragma unroll
        for (int p = 0; p < 8; ++p) {
            int r0  = r0_ + p * 32;
            int kr0 = iclamp(kg0 + r0,     0, L - 1);
            int kr1 = iclamp(kg0 + r0 + 1, 0, L - 1);
            float4 v0 = *(const float4*)(v_ + bn + (size_t)kr0 * RS + h4);
            float4 v1 = *(const float4*)(v_ + bn + (size_t)kr1 * RS + h4);
            *(f16x2*)(V_lds + vaddr(h4 + 0, r0 * 2)) = (f16x2){(f16)v0.x, (f16)v1.x};
            *(f16x2*)(V_lds + vaddr(h4 + 1, r0 * 2)) = (f16x2){(f16)v0.y, (f16)v1.y};
            *(f16x2*)(V_lds + vaddr(h4 + 2, r0 * 2)) = (f16x2){(f16)v0.z, (f16)v1.z};
            *(f16x2*)(V_lds + vaddr(h4 + 3, r0 * 2)) = (f16x2){(f16)v0.w, (f16)v1.w};
        }
    }

    // window mask bounds: allowed local keys j with j-iq in [0,126] and kg0+j in [0,L)
    const int iq  = wq * 32 + lq;
    const int jlo = (c == 0) ? WR : 0;
    const int jhi = (KW < L - kg0) ? KW : (L - kg0);
    const int lo  = (iq > jlo) ? iq : jlo;
    const int hb  = (iq + 126 < jhi - 1) ? (iq + 126) : (jhi - 1);
    const unsigned span = (unsigned)(hb - lo);

    f32x16 o0, o1;
    #pragma unroll
    for (int r = 0; r < 16; ++r) { o0[r] = 0.f; o1[r] = 0.f; }
    float dsum = 0.f;

    __syncthreads();

    // ---- Q fragments from LDS (B-operand: lane holds Q[q=lq][h=16tq+8hi+j]) ----
    f16x8 qf[4];
    {
        const int qrow = wq * 32 + lq;
        #pragma unroll
        for (int tq = 0; tq < 4; ++tq)
            qf[tq] = *(const f16x8*)(Q_lds + rmaddr(qrow, 32 * tq + 16 * hi));
    }

    #pragma unroll
    for (int i = 0; i < 5; ++i) {
        const int kt = wq + i;
        // ---- K fragments from LDS (A-operand: lane holds K[k=kt*32+lq][h=16tq+8hi+j]) ----
        const int krow = kt * 32 + lq;
        f16x8 kf[4];
        #pragma unroll
        for (int tq = 0; tq < 4; ++tq)
            kf[tq] = *(const f16x8*)(K_lds + rmaddr(krow, 32 * tq + 16 * hi));

        // ---- S^T tile = K_tile(32k x 64h) . Q^T ----
        f32x16 s;
        #pragma unroll
        for (int r = 0; r < 16; ++r) s[r] = 0.f;
        #pragma unroll
        for (int tq = 0; tq < 4; ++tq)
            s = __builtin_amdgcn_mfma_f32_32x32x16_f16(kf[tq], qf[tq], s, 0, 0, 0);

        // ---- mask + exp2 + denominator (per-lane: q = lq) ----
        const int jb = kt * 32 + 4 * hi;
        float pe[16];
        #pragma unroll
        for (int r = 0; r < 16; ++r) {
            int j = jb + (r & 3) + ((r >> 2) << 3);      // D-row -> local key index
            float e = fexp2(s[r]);
            e = ((unsigned)(j - lo) <= span) ? e : 0.f;
            dsum += e;
            pe[r] = e;
        }
        // ---- P fragments: pack to f16 pairs, exchange across lane halves -> A-operand ----
        int d0 = packh2(pe[0],  pe[1]),  d1 = packh2(pe[2],  pe[3]);
        int d2 = packh2(pe[4],  pe[5]),  d3 = packh2(pe[6],  pe[7]);
        int d4 = packh2(pe[8],  pe[9]),  d5 = packh2(pe[10], pe[11]);
        int d6 = packh2(pe[12], pe[13]), d7 = packh2(pe[14], pe[15]);
        swap_halves(d0, d2, hi); swap_halves(d1, d3, hi);
        swap_halves(d4, d6, hi); swap_halves(d5, d7, hi);
        f16x8 pa0 = __builtin_bit_cast(f16x8, (int4v){d0, d1, d2, d3});   // keys kt*32 + 0..15
        f16x8 pa1 = __builtin_bit_cast(f16x8, (int4v){d4, d5, d6, d7});   // keys kt*32 + 16..31

        // ---- PV: O[32q][64h] += P . V, B-operand from swizzled transposed V in LDS ----
        const int kb = kt * 64 + hi * 16;   // key byte base for this lane's k-slots
        f16x8 vb00 = *(const f16x8*)(V_lds + vaddr(lq,      kb));
        f16x8 vb01 = *(const f16x8*)(V_lds + vaddr(lq,      kb + 32));
        f16x8 vb10 = *(const f16x8*)(V_lds + vaddr(32 + lq, kb));
        f16x8 vb11 = *(const f16x8*)(V_lds + vaddr(32 + lq, kb + 32));
        o0 = __builtin_amdgcn_mfma_f32_32x32x16_f16(pa0, vb00, o0, 0, 0, 0);
        o0 = __builtin_amdgcn_mfma_f32_32x32x16_f16(pa1, vb01, o0, 0, 0, 0);
        o1 = __builtin_amdgcn_mfma_f32_32x32x16_f16(pa0, vb10, o1, 0, 0, 0);
        o1 = __builtin_amdgcn_mfma_f32_32x32x16_f16(pa1, vb11, o1, 0, 0, 0);
    }

    // ---- denominators: full per-query sum, reciprocal, per-row redistribute ----
    float dtot = dsum + __shfl_xor(dsum, 32, 64);
    float dinv = 1.0f / dtot;

    __syncthreads();   // all waves done reading Q/K/V LDS; reuse for O staging

    // normalized O fragments -> swizzled LDS (row q = wq*32 + (r&3)+8*(r>>2)+4*hi)
    #pragma unroll
    for (int r = 0; r < 16; ++r) {
        int qloc = (r & 3) + ((r >> 2) << 3) + 4 * hi;
        float rd = __shfl(dinv, qloc, 64);     // dinv of query qloc lives in lane qloc
        int row = wq * 32 + qloc;
        O_lds[oaddr(row, lq)]      = o0[r] * rd;
        O_lds[oaddr(row, 32 + lq)] = o1[r] * rd;
    }
    __syncthreads();

    // coalesced float4 stores: out[b][c*128+row][n][h]
    const size_t ob = ((size_t)b * L + (size_t)c * CQ) * RS + (size_t)n * H;
    #pragma unroll
    for (int it = 0; it < 8; ++it) {
        int flat = it * 256 + t;
        int row  = flat >> 4;
        int hh   = (flat & 15) << 2;
        float4 val = *(const float4*)(O_lds + oaddr(row, hh));
        *(float4*)(o_ + ob + (size_t)row * RS + hh) = val;
    }
}

extern "C" void kernel_launch(void* const* d_in, const int* in_sizes, int n_in,
                              void* d_out, int out_size, void* d_ws, size_t ws_size,
                              hipStream_t stream) {
    const float* q = (const float*)d_in[0];
    const float* k = (const float*)d_in[1];
    const float* v = (const float*)d_in[2];
    float* o = (float*)d_out;
    (void)in_sizes; (void)n_in; (void)out_size; (void)d_ws; (void)ws_size;
    wattn_kernel<<<dim3(NB * NH * NC), dim3(256), 0, stream>>>(q, k, v, o);
}